// Round 11
// baseline (121.059 us; speedup 1.0000x reference)
//
#include <hip/hip_runtime.h>
#include <hip/hip_bf16.h>
#include <math.h>

// B=2, S=1024, D=512, H=8, hd=64.  M = B*S = 2048.
// Chunked causal linear attention, chunk C=128, NC=8, BH=16.
// 4 launches: prep -> qkv+xg GEMM (zeroes flags) -> mc|attn (spin-fused) -> proj|gate (spin-fused).

typedef __bf16 bf16x8 __attribute__((ext_vector_type(8)));
typedef __bf16 bf16x4 __attribute__((ext_vector_type(4)));
typedef float f32x4 __attribute__((ext_vector_type(4)));

#define MFMA16(a, b, c) __builtin_amdgcn_mfma_f32_16x16x32_bf16(a, b, c, 0, 0, 0)
#define FLAG_MAGIC 0x13572468u

__device__ __forceinline__ float elu1(float v) { return v > 0.f ? v + 1.f : __expf(v); }

__device__ __forceinline__ void gload16(const void* g, void* l) {
    __builtin_amdgcn_global_load_lds((const __attribute__((address_space(1))) void*)g,
                                     (__attribute__((address_space(3))) void*)l, 16, 0, 0);
}

// ---------------------------------------------------------------- prep: x->bf16 + weight transposes
__global__ __launch_bounds__(256) void prep_kernel(
    const float* __restrict__ x, const float* __restrict__ Wq, const float* __restrict__ Wk,
    const float* __restrict__ Wv, const float* __restrict__ Wo, const float* __restrict__ Wg,
    __bf16* __restrict__ xb, __bf16* __restrict__ wqkvT, __bf16* __restrict__ woT,
    __bf16* __restrict__ wg2T) {
    int z = blockIdx.z;
    if (z == 5) {
        int bid = blockIdx.y * 16 + blockIdx.x;
        int base = (bid * 256 + threadIdx.x) * 8;
        bf16x8 o;
#pragma unroll
        for (int j = 0; j < 8; j++) o[j] = (__bf16)x[base + j];
        *(bf16x8*)&xb[base] = o;
        return;
    }
    const float* in;
    int R = 512;
    if (z == 0) in = Wq;
    else if (z == 1) in = Wk;
    else if (z == 2) in = Wv;
    else if (z == 3) in = Wo;
    else { in = Wg; R = 1024; }
    if ((int)blockIdx.y * 32 >= R) return;
    __shared__ float t[32][33];
    int bx = blockIdx.x, by = blockIdx.y;
    int tx = threadIdx.x & 31, ty = threadIdx.x >> 5;
#pragma unroll
    for (int i = 0; i < 32; i += 8)
        t[ty + i][tx] = in[(size_t)(by * 32 + ty + i) * 512 + bx * 32 + tx];
    __syncthreads();
#pragma unroll
    for (int i = 0; i < 32; i += 8) {
        int n = bx * 32 + ty + i;
        int kk = by * 32 + tx;
        __bf16 val = (__bf16)t[tx][ty + i];
        if (z == 0) wqkvT[(size_t)n * 512 + kk] = val;
        else if (z == 1) wqkvT[(size_t)(512 + n) * 512 + kk] = val;
        else if (z == 2) wqkvT[(size_t)(1024 + n) * 512 + kk] = val;
        else if (z == 3) woT[(size_t)n * 512 + kk] = val;
        else if (kk < 512) wqkvT[(size_t)(1536 + n) * 512 + kk] = val;
        else wg2T[(size_t)n * 512 + (kk - 512)] = val;
    }
}

// ---------------------------------------------------------------- qkv+xg GEMM (64x64, depth 4); zeroes flags
__global__ __launch_bounds__(256) void qkv_kernel(
    const __bf16* __restrict__ A, const __bf16* __restrict__ Bw,
    __bf16* __restrict__ q_out, __bf16* __restrict__ k_out,
    __bf16* __restrict__ kt_out, __bf16* __restrict__ vt_out, __bf16* __restrict__ xg_out,
    unsigned* __restrict__ flags) {
    __shared__ __bf16 sA[4 * 64 * 32];
    __shared__ __bf16 sB[4 * 64 * 32];
    __shared__ __bf16 sE[64 * 72];
    int bm = blockIdx.x, bn = blockIdx.y;
    int tid = threadIdx.x, w = tid >> 6, l = tid & 63;
    if (bm == 0 && bn == 0) {
        for (int i = tid; i < 384; i += 256) flags[i] = 0u;
    }
    int wr = (w >> 1) * 32, wc = (w & 1) * 32;
    int r = tid >> 2, c = (tid & 3) * 8;
    f32x4 acc[2][2] = {};
    const int nt = 16;

    auto stage = [&](int t, int buf) {
        int k0 = t * 32;
        gload16(&A[(size_t)(bm * 64 + r) * 512 + k0 + c], &sA[buf * 2048 + w * 512]);
        gload16(&Bw[(size_t)(bn * 64 + r) * 512 + k0 + c], &sB[buf * 2048 + w * 512]);
    };
    stage(0, 0);
    stage(1, 1);
    stage(2, 2);
    for (int t = 0; t < nt; t++) {
        if (t + 2 < nt) asm volatile("s_waitcnt vmcnt(4)" ::: "memory");
        else if (t + 1 < nt) asm volatile("s_waitcnt vmcnt(2)" ::: "memory");
        else asm volatile("s_waitcnt vmcnt(0)" ::: "memory");
        asm volatile("s_barrier" ::: "memory");
        if (t + 3 < nt) stage(t + 3, (t + 3) & 3);
        int buf = t & 3;
        bf16x8 af[2], bfr[2];
#pragma unroll
        for (int mi = 0; mi < 2; mi++)
            af[mi] = *(const bf16x8*)&sA[buf * 2048 + (wr + mi * 16 + (l & 15)) * 32 + ((l >> 4) << 3)];
#pragma unroll
        for (int ni = 0; ni < 2; ni++)
            bfr[ni] = *(const bf16x8*)&sB[buf * 2048 + (wc + ni * 16 + (l & 15)) * 32 + ((l >> 4) << 3)];
#pragma unroll
        for (int mi = 0; mi < 2; mi++)
#pragma unroll
            for (int ni = 0; ni < 2; ni++)
                acc[mi][ni] = MFMA16(af[mi], bfr[ni], acc[mi][ni]);
    }

    // epilogue through LDS, coalesced stores
    __syncthreads();
#pragma unroll
    for (int mi = 0; mi < 2; mi++)
#pragma unroll
        for (int ni = 0; ni < 2; ni++)
#pragma unroll
            for (int j = 0; j < 4; j++) {
                int lr = wr + mi * 16 + ((l >> 4) << 2) + j;
                int lc = wc + ni * 16 + (l & 15);
                float v = acc[mi][ni][j];
                if (bn < 16) v = elu1(v);
                sE[lr * 72 + lc] = (__bf16)v;
            }
    __syncthreads();
    int which = bn >> 3;  // 0:q 1:k 2:v 3:xg
    int b = bm >> 4, s0b = (bm & 15) * 64, h = bn & 7;
    int bh = b * 8 + h;
    if (which == 0 || which == 1) {
        __bf16* qk = (which == 0 ? q_out : k_out) + ((size_t)(bh * 1024 + s0b)) * 64;
#pragma unroll
        for (int p = 0; p < 2; p++) {
            int idx = p * 256 + tid;
            *(bf16x8*)&qk[idx * 8] = *(const bf16x8*)&sE[(idx >> 3) * 72 + (idx & 7) * 8];
        }
    }
    if (which == 1 || which == 2) {
        __bf16* tdst = (which == 1 ? kt_out : vt_out) + (size_t)(bh * 64) * 1024 + s0b;
        alignas(16) __bf16 tmp[16];
#pragma unroll
        for (int sj = 0; sj < 16; sj++) tmp[sj] = sE[(w * 16 + sj) * 72 + l];
        *(bf16x8*)&tdst[(size_t)l * 1024 + w * 16] = *(const bf16x8*)&tmp[0];
        *(bf16x8*)&tdst[(size_t)l * 1024 + w * 16 + 8] = *(const bf16x8*)&tmp[8];
    }
    if (which == 3) {
        __bf16* dst = xg_out + (size_t)(bm * 64) * 512 + (bn - 24) * 64;
#pragma unroll
        for (int p = 0; p < 2; p++) {
            int idx = p * 256 + tid;
            *(bf16x8*)&dst[(size_t)(idx >> 3) * 512 + (idx & 7) * 8] =
                *(const bf16x8*)&sE[(idx >> 3) * 72 + (idx & 7) * 8];
        }
    }
}

// ---------------------------------------------------------------- fused mc | attn (384 blocks)
// blocks 0..127: M_c = V^T K + ksum_c, then release flags[bh*8+ch].
// blocks 128..383: attn (bh, ch, half); spins on flags for chunks < ch.
__global__ __launch_bounds__(256) void mcattn_kernel(
    const __bf16* __restrict__ qb, const __bf16* __restrict__ kb,
    const __bf16* __restrict__ ktb, const __bf16* __restrict__ vtb,
    float* __restrict__ Mc, float* __restrict__ ksc, __bf16* __restrict__ attn_out,
    unsigned* __restrict__ flags) {
    int blk = blockIdx.x;
    int tid = threadIdx.x, w = tid >> 6, l = tid & 63;

    __shared__ __bf16 sQ[64 * 72];
    __shared__ __bf16 sP[64 * 136];
    __shared__ __bf16 sM[64 * 72];
    __shared__ float den[64];
    __shared__ float rsum[64];
    __shared__ float ksst[64];

    if (blk < 128) {
        // ---------------- mc producer
        int bh = blk >> 3, ch = blk & 7;
        const __bf16* vb = vtb + (size_t)bh * 65536 + ch * 128;
        const __bf16* kp = ktb + (size_t)bh * 65536 + ch * 128;
        f32x4 macc[4] = {};
#pragma unroll
        for (int ks = 0; ks < 4; ks++) {
            bf16x8 a = *(const bf16x8*)&vb[(size_t)(w * 16 + (l & 15)) * 1024 + ks * 32 + ((l >> 4) << 3)];
#pragma unroll
            for (int ni = 0; ni < 4; ni++) {
                bf16x8 bb = *(const bf16x8*)&kp[(size_t)(ni * 16 + (l & 15)) * 1024 + ks * 32 + ((l >> 4) << 3)];
                macc[ni] = MFMA16(a, bb, macc[ni]);
            }
        }
        float* mout = Mc + (size_t)blk * 4096;
#pragma unroll
        for (int ni = 0; ni < 4; ni++)
#pragma unroll
            for (int j = 0; j < 4; j++)
                mout[(size_t)(w * 16 + ((l >> 4) << 2) + j) * 64 + ni * 16 + (l & 15)] = macc[ni][j];
        if (tid < 64) {
            float s = 0.f;
            const __bf16* kr = ktb + (size_t)(bh * 64 + tid) * 1024 + ch * 128;
#pragma unroll
            for (int t = 0; t < 16; t++) {
                bf16x8 v = *(const bf16x8*)&kr[t * 8];
#pragma unroll
                for (int j = 0; j < 8; j++) s += (float)v[j];
            }
            ksc[blk * 64 + tid] = s;
        }
        __syncthreads();
        __threadfence();
        if (tid == 0) atomicExch(&flags[blk], FLAG_MAGIC);
        return;
    }

    // ---------------- attn consumer
    int ablk = blk - 128;
    int bh = ablk >> 4, ch = (ablk >> 1) & 7, half = ablk & 1;
    int b = bh >> 3, h = bh & 7;

    const __bf16* qsrc = qb + (size_t)(bh * 1024 + ch * 128 + half * 64) * 64;
#pragma unroll
    for (int i = 0; i < 2; i++) {
        int e = i * 2048 + tid * 8;
        *(bf16x8*)&sQ[(e >> 6) * 72 + (e & 63)] = *(const bf16x8*)&qsrc[e];
    }
    if (ch > 0) {
        if (tid < ch) {
            while (atomicAdd(&flags[bh * 8 + tid], 0u) != FLAG_MAGIC) {}
        }
        __syncthreads();
        __threadfence();
    }
    {
        int r0 = tid >> 2, c0 = (tid & 3) * 16;
        f32x4 s0 = {}, s1 = {}, s2 = {}, s3 = {};
        const float* mcb = Mc + (size_t)(bh * 8) * 4096 + r0 * 64 + c0;
        for (int c = 0; c < ch; c++) {
            const float* p = mcb + (size_t)c * 4096;
            s0 += *(const f32x4*)&p[0];
            s1 += *(const f32x4*)&p[4];
            s2 += *(const f32x4*)&p[8];
            s3 += *(const f32x4*)&p[12];
        }
        __bf16* d = &sM[r0 * 72 + c0];
#pragma unroll
        for (int j = 0; j < 4; j++) {
            d[j] = (__bf16)s0[j];
            d[4 + j] = (__bf16)s1[j];
            d[8 + j] = (__bf16)s2[j];
            d[12 + j] = (__bf16)s3[j];
        }
    }
    if (tid < 64) {
        float s = 0.f;
        for (int c = 0; c < ch; c++) s += ksc[(bh * 8 + c) * 64 + tid];
        ksst[tid] = s;
    }
    __syncthreads();

    if (tid < 64) {
        float s = 0.f;
#pragma unroll
        for (int d0 = 0; d0 < 64; d0 += 8) {
            bf16x8 qv = *(const bf16x8*)&sQ[tid * 72 + d0];
#pragma unroll
            for (int jj = 0; jj < 8; jj++) s += (float)qv[jj] * ksst[d0 + jj];
        }
        den[tid] = s;
    }

    {
        int wr = w * 16;
        const int CFMAX = half ? (w + 4) : w;
        const int CFLIM = half ? 7 : 3;
        const __bf16* kbase = kb + (size_t)(bh * 1024 + ch * 128) * 64;
        bf16x8 aq[2];
#pragma unroll
        for (int ks = 0; ks < 2; ks++)
            aq[ks] = *(const bf16x8*)&sQ[(wr + (l & 15)) * 72 + ks * 32 + ((l >> 4) << 3)];
        f32x4 acc[8] = {};
#pragma unroll
        for (int cf = 0; cf < 8; cf++) {
            if (cf <= CFMAX && cf <= CFLIM) {
#pragma unroll
                for (int ks = 0; ks < 2; ks++) {
                    bf16x8 bfr = *(const bf16x8*)&kbase[(size_t)(cf * 16 + (l & 15)) * 64 + ks * 32 + ((l >> 4) << 3)];
                    acc[cf] = MFMA16(aq[ks], bfr, acc[cf]);
                }
            }
        }
#pragma unroll
        for (int j = 0; j < 4; j++) {
            int lrow = wr + ((l >> 4) << 2) + j;
            int grow = half * 64 + lrow;
            float rs = 0.f;
#pragma unroll
            for (int cf = 0; cf < 8; cf++) {
                if (cf <= CFMAX && cf <= CFLIM) {
                    int col = cf * 16 + (l & 15);
                    float v = acc[cf][j];
                    v = (col <= grow) ? v : 0.f;
                    rs += v;
                    sP[lrow * 136 + col] = (__bf16)v;
                }
            }
            if (CFMAX + 1 <= CFLIM) sP[lrow * 136 + (CFMAX + 1) * 16 + (l & 15)] = (__bf16)0.f;
#pragma unroll
            for (int off = 1; off < 16; off <<= 1) rs += __shfl_xor(rs, off);
            if ((l & 15) == 0) rsum[lrow] = rs;
        }
    }
    __syncthreads();

    f32x4 o[4] = {};
    {
        int wr = w * 16;
        int ksmax = half ? (2 + (w >> 1)) : (w >> 1);
        const __bf16* vbase = vtb + (size_t)bh * 65536 + ch * 128;
#pragma unroll
        for (int ks = 0; ks < 4; ks++) {
            if (ks <= ksmax) {
                bf16x8 a = *(const bf16x8*)&sP[(wr + (l & 15)) * 136 + ks * 32 + ((l >> 4) << 3)];
#pragma unroll
                for (int ni = 0; ni < 4; ni++) {
                    bf16x8 bfr = *(const bf16x8*)&vbase[(size_t)(ni * 16 + (l & 15)) * 1024 + ks * 32 + ((l >> 4) << 3)];
                    o[ni] = MFMA16(a, bfr, o[ni]);
                }
            }
        }
        if (ch > 0) {
#pragma unroll
            for (int ks = 0; ks < 2; ks++) {
                bf16x8 a = *(const bf16x8*)&sQ[(wr + (l & 15)) * 72 + ks * 32 + ((l >> 4) << 3)];
#pragma unroll
                for (int ni = 0; ni < 4; ni++) {
                    bf16x8 bfr = *(const bf16x8*)&sM[(ni * 16 + (l & 15)) * 72 + ks * 32 + ((l >> 4) << 3)];
                    o[ni] = MFMA16(a, bfr, o[ni]);
                }
            }
        }
    }

    __bf16* obase = attn_out + ((size_t)(b * 1024 + ch * 128 + half * 64)) * 512 + h * 64;
#pragma unroll
    for (int j = 0; j < 4; j++) {
        int lrow = w * 16 + ((l >> 4) << 2) + j;
        float dn = den[lrow] + rsum[lrow] + 1e-6f;
#pragma unroll
        for (int ni = 0; ni < 4; ni++) {
            int col = ni * 16 + (l & 15);
            obase[(size_t)lrow * 512 + col] = (__bf16)(o[ni][j] / dn);
        }
    }
}

// ---------------------------------------------------------------- fused proj | gate (512 blocks)
// blocks 0..255: proj tile (bm=blk>>3, bn=blk&7) -> projb bf16; release flags[128+blk].
// blocks 256..511: gate tile; spins on its row-panel's 8 proj flags.
__global__ __launch_bounds__(256) void projgate_kernel(
    const __bf16* __restrict__ attn, const __bf16* __restrict__ woT,
    const __bf16* __restrict__ wg2T, const float* __restrict__ bo,
    const float* __restrict__ bg, const __bf16* __restrict__ xgb,
    const float* __restrict__ x, __bf16* __restrict__ projb, float* __restrict__ out,
    unsigned* __restrict__ flags) {
    __shared__ __bf16 sA[4 * 64 * 32];
    __shared__ __bf16 sB[4 * 64 * 32];
    int blk = blockIdx.x;
    int tid = threadIdx.x, w = tid >> 6, l = tid & 63;
    int wr = (w >> 1) * 32, wc = (w & 1) * 32;
    int r = tid >> 2, c = (tid & 3) * 8;
    const bool is_proj = blk < 256;
    int pblk = is_proj ? blk : blk - 256;
    int bm = pblk >> 3, bn = pblk & 7;
    const __bf16* A = is_proj ? attn : projb;
    const __bf16* Bw = is_proj ? woT : wg2T;

    if (!is_proj) {
        if (tid < 8) {
            while (atomicAdd(&flags[128 + bm * 8 + tid], 0u) != FLAG_MAGIC) {}
        }
        __syncthreads();
        __threadfence();
    }

    f32x4 acc[2][2] = {};
    auto stage = [&](int t, int buf) {
        int k0 = t * 32;
        gload16(&A[(size_t)(bm * 64 + r) * 512 + k0 + c], &sA[buf * 2048 + w * 512]);
        gload16(&Bw[(size_t)(bn * 64 + r) * 512 + k0 + c], &sB[buf * 2048 + w * 512]);
    };
    stage(0, 0);
    stage(1, 1);
    stage(2, 2);
    for (int t = 0; t < 16; t++) {
        if (t + 2 < 16) asm volatile("s_waitcnt vmcnt(4)" ::: "memory");
        else if (t + 1 < 16) asm volatile("s_waitcnt vmcnt(2)" ::: "memory");
        else asm volatile("s_waitcnt vmcnt(0)" ::: "memory");
        asm volatile("s_barrier" ::: "memory");
        if (t + 3 < 16) stage(t + 3, (t + 3) & 3);
        int buf = t & 3;
        bf16x8 af[2], bfr[2];
#pragma unroll
        for (int mi = 0; mi < 2; mi++)
            af[mi] = *(const bf16x8*)&sA[buf * 2048 + (wr + mi * 16 + (l & 15)) * 32 + ((l >> 4) << 3)];
#pragma unroll
        for (int ni = 0; ni < 2; ni++)
            bfr[ni] = *(const bf16x8*)&sB[buf * 2048 + (wc + ni * 16 + (l & 15)) * 32 + ((l >> 4) << 3)];
#pragma unroll
        for (int mi = 0; mi < 2; mi++)
#pragma unroll
            for (int ni = 0; ni < 2; ni++)
                acc[mi][ni] = MFMA16(af[mi], bfr[ni], acc[mi][ni]);
    }

    if (is_proj) {
#pragma unroll
        for (int mi = 0; mi < 2; mi++)
#pragma unroll
            for (int ni = 0; ni < 2; ni++)
#pragma unroll
                for (int j = 0; j < 4; j++) {
                    int gm = bm * 64 + wr + mi * 16 + ((l >> 4) << 2) + j;
                    int gn = bn * 64 + wc + ni * 16 + (l & 15);
                    projb[(size_t)gm * 512 + gn] = (__bf16)(acc[mi][ni][j] + bo[gn]);
                }
        __syncthreads();
        __threadfence();
        if (tid == 0) atomicExch(&flags[128 + pblk], FLAG_MAGIC);
    } else {
#pragma unroll
        for (int mi = 0; mi < 2; mi++)
#pragma unroll
            for (int ni = 0; ni < 2; ni++)
#pragma unroll
                for (int j = 0; j < 4; j++) {
                    int gm = bm * 64 + wr + mi * 16 + ((l >> 4) << 2) + j;
                    int gn = bn * 64 + wc + ni * 16 + (l & 15);
                    float v = acc[mi][ni][j] + (float)xgb[(size_t)gm * 512 + gn] + bg[gn];
                    float g = 1.f / (1.f + __expf(-v));
                    float xv = x[(size_t)gm * 512 + gn];
                    float pv = (float)projb[(size_t)gm * 512 + gn];
                    out[(size_t)gm * 512 + gn] = xv + g * (pv - xv);
                }
    }
}

// ----------------------------------------------------------------
extern "C" void kernel_launch(void* const* d_in, const int* in_sizes, int n_in,
                              void* d_out, int out_size, void* d_ws, size_t ws_size,
                              hipStream_t stream) {
    const float* x = (const float*)d_in[0];
    const float* Wq = (const float*)d_in[1];
    const float* Wk = (const float*)d_in[2];
    const float* Wv = (const float*)d_in[3];
    const float* Wo = (const float*)d_in[4];
    const float* bo = (const float*)d_in[5];
    const float* Wg = (const float*)d_in[6];
    const float* bg = (const float*)d_in[7];
    float* out = (float*)d_out;

    char* ws = (char*)d_ws;
    size_t off = 0;
    auto alloc = [&](size_t bytes) -> void* {
        void* p = ws + off;
        off += (bytes + 255) & ~(size_t)255;
        return p;
    };
    __bf16* xb    = (__bf16*)alloc((size_t)2048 * 512 * 2);
    __bf16* wqkvT = (__bf16*)alloc((size_t)2048 * 512 * 2);
    __bf16* woT   = (__bf16*)alloc((size_t)512 * 512 * 2);
    __bf16* wg2T  = (__bf16*)alloc((size_t)512 * 512 * 2);
    __bf16* qb    = (__bf16*)alloc((size_t)16 * 1024 * 64 * 2);
    __bf16* kb    = (__bf16*)alloc((size_t)16 * 1024 * 64 * 2);
    __bf16* ktb   = (__bf16*)alloc((size_t)16 * 64 * 1024 * 2);
    __bf16* vtb   = (__bf16*)alloc((size_t)16 * 64 * 1024 * 2);
    float*  Mc    = (float*)alloc((size_t)128 * 4096 * 4);
    float*  ksc   = (float*)alloc((size_t)128 * 64 * 4);
    __bf16* attn  = (__bf16*)alloc((size_t)2048 * 512 * 2);
    __bf16* projb = (__bf16*)alloc((size_t)2048 * 512 * 2);
    __bf16* xgb   = (__bf16*)alloc((size_t)2048 * 512 * 2);
    unsigned* flags = (unsigned*)alloc((size_t)384 * 4);

    prep_kernel<<<dim3(16, 32, 6), 256, 0, stream>>>(x, Wq, Wk, Wv, Wo, Wg, xb, wqkvT, woT, wg2T);
    qkv_kernel<<<dim3(32, 32), 256, 0, stream>>>(xb, wqkvT, qb, kb, ktb, vtb, xgb, flags);
    mcattn_kernel<<<384, 256, 0, stream>>>(qb, kb, ktb, vtb, Mc, ksc, attn, flags);
    projgate_kernel<<<512, 256, 0, stream>>>(attn, woT, wg2T, bo, bg, xgb, x, projb, out, flags);
}

// Round 12
// 58.121 us; speedup vs baseline: 2.0829x; 2.0829x over previous
//
#include <hip/hip_runtime.h>
#include <hip/hip_bf16.h>
#include <math.h>

// B=2, S=1024, D=512, H=8, hd=64.  M = B*S = 2048.
// Chunked causal linear attention, chunk C=128, NC=8, BH=16.
// 6 launches: prep -> qkv+xg GEMM (N=2048) -> mc -> attn(256) -> proj -> gate.
// GEMMs: BK=64, depth-3 counted-vmcnt pipeline, T2 XOR-swizzled LDS
// (linear gload_lds dest + pre-swizzled global source + swizzled ds_read).

typedef __bf16 bf16x8 __attribute__((ext_vector_type(8)));
typedef __bf16 bf16x4 __attribute__((ext_vector_type(4)));
typedef float f32x4 __attribute__((ext_vector_type(4)));

#define MFMA16(a, b, c) __builtin_amdgcn_mfma_f32_16x16x32_bf16(a, b, c, 0, 0, 0)

__device__ __forceinline__ float elu1(float v) { return v > 0.f ? v + 1.f : __expf(v); }

__device__ __forceinline__ void gload16(const void* g, void* l) {
    __builtin_amdgcn_global_load_lds((const __attribute__((address_space(1))) void*)g,
                                     (__attribute__((address_space(3))) void*)l, 16, 0, 0);
}

// ---------------------------------------------------------------- prep: x->bf16 + weight transposes
__global__ __launch_bounds__(256) void prep_kernel(
    const float* __restrict__ x, const float* __restrict__ Wq, const float* __restrict__ Wk,
    const float* __restrict__ Wv, const float* __restrict__ Wo, const float* __restrict__ Wg,
    __bf16* __restrict__ xb, __bf16* __restrict__ wqkvT, __bf16* __restrict__ woT,
    __bf16* __restrict__ wg2T) {
    int z = blockIdx.z;
    if (z == 5) {
        int bid = blockIdx.y * 16 + blockIdx.x;
        int base = (bid * 256 + threadIdx.x) * 8;
        bf16x8 o;
#pragma unroll
        for (int j = 0; j < 8; j++) o[j] = (__bf16)x[base + j];
        *(bf16x8*)&xb[base] = o;
        return;
    }
    const float* in;
    int R = 512;
    if (z == 0) in = Wq;
    else if (z == 1) in = Wk;
    else if (z == 2) in = Wv;
    else if (z == 3) in = Wo;
    else { in = Wg; R = 1024; }
    if ((int)blockIdx.y * 32 >= R) return;
    __shared__ float t[32][33];
    int bx = blockIdx.x, by = blockIdx.y;
    int tx = threadIdx.x & 31, ty = threadIdx.x >> 5;
#pragma unroll
    for (int i = 0; i < 32; i += 8)
        t[ty + i][tx] = in[(size_t)(by * 32 + ty + i) * 512 + bx * 32 + tx];
    __syncthreads();
#pragma unroll
    for (int i = 0; i < 32; i += 8) {
        int n = bx * 32 + ty + i;
        int kk = by * 32 + tx;
        __bf16 val = (__bf16)t[tx][ty + i];
        if (z == 0) wqkvT[(size_t)n * 512 + kk] = val;
        else if (z == 1) wqkvT[(size_t)(512 + n) * 512 + kk] = val;
        else if (z == 2) wqkvT[(size_t)(1024 + n) * 512 + kk] = val;
        else if (z == 3) woT[(size_t)n * 512 + kk] = val;
        else if (kk < 512) wqkvT[(size_t)(1536 + n) * 512 + kk] = val;
        else wg2T[(size_t)n * 512 + (kk - 512)] = val;
    }
}

// ---------------------------------------------------------------- pipelined GEMM (64x64, BK=64, depth 3)
// A row-major [M][K] bf16 ; Bw row-major [N][K] bf16 (B^T) ; fp32 accum.
// LDS tiles [64][64] (128B rows), st-swizzle byte ^= (row&7)<<4 -> conflict-free b128 reads.
// MODE 0: qkv+xg epilogue (LDS-coalesced); MODE 1: proj -> bf16; MODE 2: gate (+xg, sigmoid, mix).
template <int MODE>
__global__ __launch_bounds__(256) void gemm_kernel(
    const __bf16* __restrict__ A, const __bf16* __restrict__ Bw, const float* __restrict__ bias,
    const float* __restrict__ xf, const __bf16* __restrict__ xgb, const __bf16* __restrict__ pvb,
    float* __restrict__ outf, __bf16* __restrict__ outb,
    __bf16* __restrict__ q_out, __bf16* __restrict__ k_out,
    __bf16* __restrict__ kt_out, __bf16* __restrict__ vt_out, __bf16* __restrict__ xg_out, int K) {
    __shared__ __bf16 sA[3 * 64 * 64];
    __shared__ __bf16 sB[3 * 64 * 64];
    int bm = blockIdx.x, bn = blockIdx.y;
    int tid = threadIdx.x, w = tid >> 6, l = tid & 63;
    int wr = (w >> 1) * 32, wc = (w & 1) * 32;
    f32x4 acc[2][2] = {};
    const int nt = K / 64;

    // per-lane source swizzle: lane l of wave w, round i covers row = i*32 + w*8 + (l>>3),
    // linear slot byte = (l&7)*16; data loaded = global col byte (slot ^ ((row&7)<<4)).
    auto stage = [&](int t, int buf) {
        int k0 = t * 64;
#pragma unroll
        for (int i = 0; i < 2; i++) {
            int row = i * 32 + w * 8 + (l >> 3);
            int gc = (((l & 7) << 4) ^ ((row & 7) << 4)) >> 1;  // elems
            gload16(&A[(size_t)(bm * 64 + row) * K + k0 + gc],
                    &sA[buf * 4096 + i * 2048 + w * 512]);
            gload16(&Bw[(size_t)(bn * 64 + row) * K + k0 + gc],
                    &sB[buf * 4096 + i * 2048 + w * 512]);
        }
    };

    stage(0, 0);
    stage(1, 1);
    for (int t = 0; t < nt; t++) {
        if (t + 1 < nt) asm volatile("s_waitcnt vmcnt(4)" ::: "memory");
        else asm volatile("s_waitcnt vmcnt(0)" ::: "memory");
        asm volatile("s_barrier" ::: "memory");
        if (t + 2 < nt) stage(t + 2, (t + 2) % 3);
        int buf = t % 3;
        bf16x8 af[2][2], bfr[2][2];  // [kk][frag]
#pragma unroll
        for (int kk = 0; kk < 2; kk++) {
            int cb = kk * 64 + ((l >> 4) << 4);  // logical col byte (16B slot)
#pragma unroll
            for (int mi = 0; mi < 2; mi++) {
                int rowA = wr + mi * 16 + (l & 15);
                af[kk][mi] = *(const bf16x8*)&sA[buf * 4096 + rowA * 64 +
                                                ((cb ^ ((rowA & 7) << 4)) >> 1)];
            }
#pragma unroll
            for (int ni = 0; ni < 2; ni++) {
                int rowB = wc + ni * 16 + (l & 15);
                bfr[kk][ni] = *(const bf16x8*)&sB[buf * 4096 + rowB * 64 +
                                                 ((cb ^ ((rowB & 7) << 4)) >> 1)];
            }
        }
#pragma unroll
        for (int kk = 0; kk < 2; kk++)
#pragma unroll
            for (int mi = 0; mi < 2; mi++)
#pragma unroll
                for (int ni = 0; ni < 2; ni++)
                    acc[mi][ni] = MFMA16(af[kk][mi], bfr[kk][ni], acc[mi][ni]);
    }

    if (MODE == 0) {
        // qkv+xg epilogue: fragments -> sE (aliases sA, loop done) -> coalesced stores.
        __bf16* sE = sA;
        __syncthreads();
#pragma unroll
        for (int mi = 0; mi < 2; mi++)
#pragma unroll
            for (int ni = 0; ni < 2; ni++)
#pragma unroll
                for (int j = 0; j < 4; j++) {
                    int lr = wr + mi * 16 + ((l >> 4) << 2) + j;
                    int lc = wc + ni * 16 + (l & 15);
                    float v = acc[mi][ni][j];
                    if (bn < 16) v = elu1(v);  // q,k get feature map
                    sE[lr * 72 + lc] = (__bf16)v;
                }
        __syncthreads();
        int which = bn >> 3;  // 0:q 1:k 2:v 3:xg
        int b = bm >> 4, s0b = (bm & 15) * 64, h = bn & 7;
        int bh = b * 8 + h;
        if (which == 0 || which == 1) {
            __bf16* qk = (which == 0 ? q_out : k_out) + ((size_t)(bh * 1024 + s0b)) * 64;
#pragma unroll
            for (int p = 0; p < 2; p++) {
                int idx = p * 256 + tid;
                *(bf16x8*)&qk[idx * 8] = *(const bf16x8*)&sE[(idx >> 3) * 72 + (idx & 7) * 8];
            }
        }
        if (which == 1 || which == 2) {
            __bf16* tdst = (which == 1 ? kt_out : vt_out) + (size_t)(bh * 64) * 1024 + s0b;
            alignas(16) __bf16 tmp[16];
#pragma unroll
            for (int sj = 0; sj < 16; sj++) tmp[sj] = sE[(w * 16 + sj) * 72 + l];
            *(bf16x8*)&tdst[(size_t)l * 1024 + w * 16] = *(const bf16x8*)&tmp[0];
            *(bf16x8*)&tdst[(size_t)l * 1024 + w * 16 + 8] = *(const bf16x8*)&tmp[8];
        }
        if (which == 3) {
            __bf16* dst = xg_out + (size_t)(bm * 64) * 512 + (bn - 24) * 64;
#pragma unroll
            for (int p = 0; p < 2; p++) {
                int idx = p * 256 + tid;
                *(bf16x8*)&dst[(size_t)(idx >> 3) * 512 + (idx & 7) * 8] =
                    *(const bf16x8*)&sE[(idx >> 3) * 72 + (idx & 7) * 8];
            }
        }
    } else {
#pragma unroll
        for (int mi = 0; mi < 2; mi++)
#pragma unroll
            for (int ni = 0; ni < 2; ni++)
#pragma unroll
                for (int j = 0; j < 4; j++) {
                    int gm = bm * 64 + wr + mi * 16 + ((l >> 4) << 2) + j;
                    int gn = bn * 64 + wc + ni * 16 + (l & 15);
                    if (MODE == 1) {
                        float v = acc[mi][ni][j] + bias[gn];
                        outb[(size_t)gm * 512 + gn] = (__bf16)v;
                    } else {
                        float v = acc[mi][ni][j] + (float)xgb[(size_t)gm * 512 + gn] + bias[gn];
                        float g = 1.f / (1.f + __expf(-v));
                        float xv = xf[(size_t)gm * 512 + gn];
                        float pv = (float)pvb[(size_t)gm * 512 + gn];
                        outf[(size_t)gm * 512 + gn] = xv + g * (pv - xv);
                    }
                }
    }
}

// ---------------------------------------------------------------- per-chunk M_c = V^T K + ksum_c (128 blocks)
__global__ __launch_bounds__(256) void mc_kernel(const __bf16* __restrict__ ktb,
                                                 const __bf16* __restrict__ vtb,
                                                 float* __restrict__ Mc, float* __restrict__ ksc) {
    int blk = blockIdx.x;
    int bh = blk >> 3, ch = blk & 7;
    int tid = threadIdx.x, w = tid >> 6, l = tid & 63;
    const __bf16* vb = vtb + (size_t)bh * 65536 + ch * 128;
    const __bf16* kp = ktb + (size_t)bh * 65536 + ch * 128;
    f32x4 macc[4] = {};
#pragma unroll
    for (int ks = 0; ks < 4; ks++) {
        bf16x8 a = *(const bf16x8*)&vb[(size_t)(w * 16 + (l & 15)) * 1024 + ks * 32 + ((l >> 4) << 3)];
#pragma unroll
        for (int ni = 0; ni < 4; ni++) {
            bf16x8 bb = *(const bf16x8*)&kp[(size_t)(ni * 16 + (l & 15)) * 1024 + ks * 32 + ((l >> 4) << 3)];
            macc[ni] = MFMA16(a, bb, macc[ni]);
        }
    }
    float* mout = Mc + (size_t)blk * 4096;
#pragma unroll
    for (int ni = 0; ni < 4; ni++)
#pragma unroll
        for (int j = 0; j < 4; j++)
            mout[(size_t)(w * 16 + ((l >> 4) << 2) + j) * 64 + ni * 16 + (l & 15)] = macc[ni][j];
    if (tid < 64) {
        float s = 0.f;
        const __bf16* kr = ktb + (size_t)(bh * 64 + tid) * 1024 + ch * 128;
#pragma unroll
        for (int t = 0; t < 16; t++) {
            bf16x8 v = *(const bf16x8*)&kr[t * 8];
#pragma unroll
            for (int j = 0; j < 8; j++) s += (float)v[j];
        }
        ksc[blk * 64 + tid] = s;
    }
}

// ---------------------------------------------------------------- attention: 256 blocks (bh, ch, half)
__global__ __launch_bounds__(256) void attn_kernel(
    const __bf16* __restrict__ qb, const __bf16* __restrict__ kb,
    const __bf16* __restrict__ vtb, const float* __restrict__ Mc,
    const float* __restrict__ ksc, __bf16* __restrict__ attn_out) {
    int blk = blockIdx.x;
    int bh = blk >> 4, ch = (blk >> 1) & 7, half = blk & 1;
    int b = bh >> 3, h = bh & 7;
    int tid = threadIdx.x, w = tid >> 6, l = tid & 63;

    __shared__ __bf16 sQ[64 * 72];
    __shared__ __bf16 sP[64 * 136];
    __shared__ __bf16 sM[64 * 72];
    __shared__ float den[64];
    __shared__ float rsum[64];
    __shared__ float ksst[64];

    const __bf16* qsrc = qb + (size_t)(bh * 1024 + ch * 128 + half * 64) * 64;
#pragma unroll
    for (int i = 0; i < 2; i++) {
        int e = i * 2048 + tid * 8;
        *(bf16x8*)&sQ[(e >> 6) * 72 + (e & 63)] = *(const bf16x8*)&qsrc[e];
    }
    {
        int r0 = tid >> 2, c0 = (tid & 3) * 16;
        f32x4 s0 = {}, s1 = {}, s2 = {}, s3 = {};
        const float* mcb = Mc + (size_t)(bh * 8) * 4096 + r0 * 64 + c0;
        for (int c = 0; c < ch; c++) {
            const float* p = mcb + (size_t)c * 4096;
            s0 += *(const f32x4*)&p[0];
            s1 += *(const f32x4*)&p[4];
            s2 += *(const f32x4*)&p[8];
            s3 += *(const f32x4*)&p[12];
        }
        __bf16* d = &sM[r0 * 72 + c0];
#pragma unroll
        for (int j = 0; j < 4; j++) {
            d[j] = (__bf16)s0[j];
            d[4 + j] = (__bf16)s1[j];
            d[8 + j] = (__bf16)s2[j];
            d[12 + j] = (__bf16)s3[j];
        }
    }
    if (tid < 64) {
        float s = 0.f;
        for (int c = 0; c < ch; c++) s += ksc[(bh * 8 + c) * 64 + tid];
        ksst[tid] = s;
    }
    __syncthreads();

    if (tid < 64) {
        float s = 0.f;
#pragma unroll
        for (int d0 = 0; d0 < 64; d0 += 8) {
            bf16x8 qv = *(const bf16x8*)&sQ[tid * 72 + d0];
#pragma unroll
            for (int jj = 0; jj < 8; jj++) s += (float)qv[jj] * ksst[d0 + jj];
        }
        den[tid] = s;
    }

    {
        int wr = w * 16;
        const int CFMAX = half ? (w + 4) : w;
        const int CFLIM = half ? 7 : 3;
        const __bf16* kbase = kb + (size_t)(bh * 1024 + ch * 128) * 64;
        bf16x8 aq[2];
#pragma unroll
        for (int ks = 0; ks < 2; ks++)
            aq[ks] = *(const bf16x8*)&sQ[(wr + (l & 15)) * 72 + ks * 32 + ((l >> 4) << 3)];
        f32x4 acc[8] = {};
#pragma unroll
        for (int cf = 0; cf < 8; cf++) {
            if (cf <= CFMAX && cf <= CFLIM) {
#pragma unroll
                for (int ks = 0; ks < 2; ks++) {
                    bf16x8 bfr = *(const bf16x8*)&kbase[(size_t)(cf * 16 + (l & 15)) * 64 + ks * 32 + ((l >> 4) << 3)];
                    acc[cf] = MFMA16(aq[ks], bfr, acc[cf]);
                }
            }
        }
#pragma unroll
        for (int j = 0; j < 4; j++) {
            int lrow = wr + ((l >> 4) << 2) + j;
            int grow = half * 64 + lrow;
            float rs = 0.f;
#pragma unroll
            for (int cf = 0; cf < 8; cf++) {
                if (cf <= CFMAX && cf <= CFLIM) {
                    int col = cf * 16 + (l & 15);
                    float v = acc[cf][j];
                    v = (col <= grow) ? v : 0.f;
                    rs += v;
                    sP[lrow * 136 + col] = (__bf16)v;
                }
            }
            if (CFMAX + 1 <= CFLIM) sP[lrow * 136 + (CFMAX + 1) * 16 + (l & 15)] = (__bf16)0.f;
#pragma unroll
            for (int off = 1; off < 16; off <<= 1) rs += __shfl_xor(rs, off);
            if ((l & 15) == 0) rsum[lrow] = rs;
        }
    }
    __syncthreads();

    f32x4 o[4] = {};
    {
        int wr = w * 16;
        int ksmax = half ? (2 + (w >> 1)) : (w >> 1);
        const __bf16* vbase = vtb + (size_t)bh * 65536 + ch * 128;
#pragma unroll
        for (int ks = 0; ks < 4; ks++) {
            if (ks <= ksmax) {
                bf16x8 a = *(const bf16x8*)&sP[(wr + (l & 15)) * 136 + ks * 32 + ((l >> 4) << 3)];
#pragma unroll
                for (int ni = 0; ni < 4; ni++) {
                    bf16x8 bfr = *(const bf16x8*)&vbase[(size_t)(ni * 16 + (l & 15)) * 1024 + ks * 32 + ((l >> 4) << 3)];
                    o[ni] = MFMA16(a, bfr, o[ni]);
                }
            }
        }
        if (ch > 0) {
#pragma unroll
            for (int ks = 0; ks < 2; ks++) {
                bf16x8 a = *(const bf16x8*)&sQ[(wr + (l & 15)) * 72 + ks * 32 + ((l >> 4) << 3)];
#pragma unroll
                for (int ni = 0; ni < 4; ni++) {
                    bf16x8 bfr = *(const bf16x8*)&sM[(ni * 16 + (l & 15)) * 72 + ks * 32 + ((l >> 4) << 3)];
                    o[ni] = MFMA16(a, bfr, o[ni]);
                }
            }
        }
    }

    __bf16* obase = attn_out + ((size_t)(b * 1024 + ch * 128 + half * 64)) * 512 + h * 64;
#pragma unroll
    for (int j = 0; j < 4; j++) {
        int lrow = w * 16 + ((l >> 4) << 2) + j;
        float dn = den[lrow] + rsum[lrow] + 1e-6f;
#pragma unroll
        for (int ni = 0; ni < 4; ni++) {
            int col = ni * 16 + (l & 15);
            obase[(size_t)lrow * 512 + col] = (__bf16)(o[ni][j] / dn);
        }
    }
}

// ----------------------------------------------------------------
extern "C" void kernel_launch(void* const* d_in, const int* in_sizes, int n_in,
                              void* d_out, int out_size, void* d_ws, size_t ws_size,
                              hipStream_t stream) {
    const float* x = (const float*)d_in[0];
    const float* Wq = (const float*)d_in[1];
    const float* Wk = (const float*)d_in[2];
    const float* Wv = (const float*)d_in[3];
    const float* Wo = (const float*)d_in[4];
    const float* bo = (const float*)d_in[5];
    const float* Wg = (const float*)d_in[6];
    const float* bg = (const float*)d_in[7];
    float* out = (float*)d_out;

    char* ws = (char*)d_ws;
    size_t off = 0;
    auto alloc = [&](size_t bytes) -> void* {
        void* p = ws + off;
        off += (bytes + 255) & ~(size_t)255;
        return p;
    };
    __bf16* xb    = (__bf16*)alloc((size_t)2048 * 512 * 2);
    __bf16* wqkvT = (__bf16*)alloc((size_t)2048 * 512 * 2);
    __bf16* woT   = (__bf16*)alloc((size_t)512 * 512 * 2);
    __bf16* wg2T  = (__bf16*)alloc((size_t)512 * 512 * 2);
    __bf16* qb    = (__bf16*)alloc((size_t)16 * 1024 * 64 * 2);
    __bf16* kb    = (__bf16*)alloc((size_t)16 * 1024 * 64 * 2);
    __bf16* ktb   = (__bf16*)alloc((size_t)16 * 64 * 1024 * 2);
    __bf16* vtb   = (__bf16*)alloc((size_t)16 * 64 * 1024 * 2);
    float*  Mc    = (float*)alloc((size_t)128 * 4096 * 4);
    float*  ksc   = (float*)alloc((size_t)128 * 64 * 4);
    __bf16* attn  = (__bf16*)alloc((size_t)2048 * 512 * 2);
    __bf16* projb = (__bf16*)alloc((size_t)2048 * 512 * 2);
    __bf16* xgb   = (__bf16*)alloc((size_t)2048 * 512 * 2);

    prep_kernel<<<dim3(16, 32, 6), 256, 0, stream>>>(x, Wq, Wk, Wv, Wo, Wg, xb, wqkvT, woT, wg2T);
    gemm_kernel<0><<<dim3(32, 32), 256, 0, stream>>>(
        xb, wqkvT, nullptr, nullptr, nullptr, nullptr, nullptr, nullptr,
        qb, kb, ktb, vtb, xgb, 512);
    mc_kernel<<<128, 256, 0, stream>>>(ktb, vtb, Mc, ksc);
    attn_kernel<<<256, 256, 0, stream>>>(qb, kb, vtb, Mc, ksc, attn);
    gemm_kernel<1><<<dim3(32, 8), 256, 0, stream>>>(
        attn, woT, bo, nullptr, nullptr, nullptr, nullptr, projb,
        nullptr, nullptr, nullptr, nullptr, nullptr, 512);
    gemm_kernel<2><<<dim3(32, 8), 256, 0, stream>>>(
        projb, wg2T, bg, x, xgb, projb, out, nullptr,
        nullptr, nullptr, nullptr, nullptr, nullptr, 512);
}

// Round 13
// 54.696 us; speedup vs baseline: 2.2133x; 1.0626x over previous
//
#include <hip/hip_runtime.h>
#include <hip/hip_bf16.h>
#include <math.h>

// B=2, S=1024, D=512, H=8, hd=64.  M = B*S = 2048.
// Chunked causal linear attention, chunk C=128, NC=8, BH=16.
// 6 launches: prep -> qkv+xg (128x128, 8-wave, BK=64, swizzled) -> mc -> attn(256) -> proj -> gate.

typedef __bf16 bf16x8 __attribute__((ext_vector_type(8)));
typedef __bf16 bf16x4 __attribute__((ext_vector_type(4)));
typedef float f32x4 __attribute__((ext_vector_type(4)));

#define MFMA16(a, b, c) __builtin_amdgcn_mfma_f32_16x16x32_bf16(a, b, c, 0, 0, 0)

__device__ __forceinline__ float elu1(float v) { return v > 0.f ? v + 1.f : __expf(v); }

__device__ __forceinline__ void gload16(const void* g, void* l) {
    __builtin_amdgcn_global_load_lds((const __attribute__((address_space(1))) void*)g,
                                     (__attribute__((address_space(3))) void*)l, 16, 0, 0);
}

// ---------------------------------------------------------------- prep: x->bf16 + weight transposes
__global__ __launch_bounds__(256) void prep_kernel(
    const float* __restrict__ x, const float* __restrict__ Wq, const float* __restrict__ Wk,
    const float* __restrict__ Wv, const float* __restrict__ Wo, const float* __restrict__ Wg,
    __bf16* __restrict__ xb, __bf16* __restrict__ wqkvT, __bf16* __restrict__ woT,
    __bf16* __restrict__ wg2T) {
    int z = blockIdx.z;
    if (z == 5) {
        int bid = blockIdx.y * 16 + blockIdx.x;
        int base = (bid * 256 + threadIdx.x) * 8;
        bf16x8 o;
#pragma unroll
        for (int j = 0; j < 8; j++) o[j] = (__bf16)x[base + j];
        *(bf16x8*)&xb[base] = o;
        return;
    }
    const float* in;
    int R = 512;
    if (z == 0) in = Wq;
    else if (z == 1) in = Wk;
    else if (z == 2) in = Wv;
    else if (z == 3) in = Wo;
    else { in = Wg; R = 1024; }
    if ((int)blockIdx.y * 32 >= R) return;
    __shared__ float t[32][33];
    int bx = blockIdx.x, by = blockIdx.y;
    int tx = threadIdx.x & 31, ty = threadIdx.x >> 5;
#pragma unroll
    for (int i = 0; i < 32; i += 8)
        t[ty + i][tx] = in[(size_t)(by * 32 + ty + i) * 512 + bx * 32 + tx];
    __syncthreads();
#pragma unroll
    for (int i = 0; i < 32; i += 8) {
        int n = bx * 32 + ty + i;
        int kk = by * 32 + tx;
        __bf16 val = (__bf16)t[tx][ty + i];
        if (z == 0) wqkvT[(size_t)n * 512 + kk] = val;
        else if (z == 1) wqkvT[(size_t)(512 + n) * 512 + kk] = val;
        else if (z == 2) wqkvT[(size_t)(1024 + n) * 512 + kk] = val;
        else if (z == 3) woT[(size_t)n * 512 + kk] = val;
        else if (kk < 512) wqkvT[(size_t)(1536 + n) * 512 + kk] = val;
        else wg2T[(size_t)n * 512 + (kk - 512)] = val;
    }
}

// ---------------------------------------------------------------- qkv+xg GEMM: 128x128 tile, 8 waves,
// BK=64, depth-2, 64KB static LDS, T2 swizzle (linear gload dest + pre-swizzled source + swizzled read).
__global__ __launch_bounds__(512) void qkv_kernel(
    const __bf16* __restrict__ A, const __bf16* __restrict__ Bw,
    __bf16* __restrict__ q_out, __bf16* __restrict__ k_out,
    __bf16* __restrict__ kt_out, __bf16* __restrict__ vt_out, __bf16* __restrict__ xg_out) {
    __shared__ __bf16 smem[32768];  // 64KB: sA = [0,16384), sB = [16384,32768); sE aliases base
    __bf16* sA = smem;
    __bf16* sB = smem + 16384;
    int bm = blockIdx.x, bn = blockIdx.y;
    int tid = threadIdx.x, w = tid >> 6, l = tid & 63;
    int wr = (w >> 2) * 64, wc = (w & 3) * 32;
    f32x4 acc[4][2] = {};
    const int nt = 8;

    auto stage = [&](int t, int buf) {
        int k0 = t * 64;
#pragma unroll
        for (int i = 0; i < 2; i++) {
            int row = i * 64 + w * 8 + (l >> 3);
            int gc = (((l & 7) << 4) ^ ((row & 7) << 4)) >> 1;  // swizzled source col (elems)
            gload16(&A[(size_t)(bm * 128 + row) * 512 + k0 + gc],
                    &sA[buf * 8192 + i * 4096 + w * 512]);
            gload16(&Bw[(size_t)(bn * 128 + row) * 512 + k0 + gc],
                    &sB[buf * 8192 + i * 4096 + w * 512]);
        }
    };

    stage(0, 0);
    for (int t = 0; t < nt; t++) {
        asm volatile("s_waitcnt vmcnt(0)" ::: "memory");
        asm volatile("s_barrier" ::: "memory");
        if (t + 1 < nt) stage(t + 1, (t + 1) & 1);
        int buf = t & 1;
#pragma unroll
        for (int kk = 0; kk < 2; kk++) {
            int cb = kk * 64 + ((l >> 4) << 4);  // logical col byte
            bf16x8 af[4], bfr[2];
#pragma unroll
            for (int mi = 0; mi < 4; mi++) {
                int rowA = wr + mi * 16 + (l & 15);
                af[mi] = *(const bf16x8*)&sA[buf * 8192 + rowA * 64 +
                                            ((cb ^ ((rowA & 7) << 4)) >> 1)];
            }
#pragma unroll
            for (int ni = 0; ni < 2; ni++) {
                int rowB = wc + ni * 16 + (l & 15);
                bfr[ni] = *(const bf16x8*)&sB[buf * 8192 + rowB * 64 +
                                             ((cb ^ ((rowB & 7) << 4)) >> 1)];
            }
#pragma unroll
            for (int mi = 0; mi < 4; mi++)
#pragma unroll
                for (int ni = 0; ni < 2; ni++)
                    acc[mi][ni] = MFMA16(af[mi], bfr[ni], acc[mi][ni]);
        }
    }

    // epilogue: fragments -> sE [128][136] (aliases smem) -> coalesced stores.
    __bf16* sE = smem;
    __syncthreads();
#pragma unroll
    for (int mi = 0; mi < 4; mi++)
#pragma unroll
        for (int ni = 0; ni < 2; ni++)
#pragma unroll
            for (int j = 0; j < 4; j++) {
                int lr = wr + mi * 16 + ((l >> 4) << 2) + j;
                int lc = wc + ni * 16 + (l & 15);
                float v = acc[mi][ni][j];
                if (bn < 8) v = elu1(v);  // q,k sections get feature map
                sE[lr * 136 + lc] = (__bf16)v;
            }
    __syncthreads();
    int which = bn >> 2;            // 0:q 1:k 2:v 3:xg
    int h0 = (bn & 3) * 2;          // two heads per tile
    int b = bm >> 3, s0b = (bm & 7) * 128;
    int bh0 = b * 8 + h0;
    if (which == 0 || which == 1) {
        // token-major [s][d] per head
        __bf16* qk = (which == 0 ? q_out : k_out);
#pragma unroll
        for (int p = 0; p < 4; p++) {
            int idx = p * 512 + tid;            // 2048 vec8 stores
            int token = idx >> 4, colv = idx & 15;
            int c2 = colv >> 3, d8 = (colv & 7) * 8;
            *(bf16x8*)&qk[((size_t)((bh0 + c2) * 1024 + s0b + token)) * 64 + d8] =
                *(const bf16x8*)&sE[token * 136 + colv * 8];
        }
    }
    if (which == 1 || which == 2) {
        // feature-major [d][s]: pass c2 = head, lane = d, wave = 16-token group
        __bf16* tbase = (which == 1 ? kt_out : vt_out);
#pragma unroll
        for (int c2 = 0; c2 < 2; c2++) {
            alignas(16) __bf16 tmp[16];
#pragma unroll
            for (int sj = 0; sj < 16; sj++) tmp[sj] = sE[(w * 16 + sj) * 136 + c2 * 64 + l];
            __bf16* tdst = tbase + ((size_t)((bh0 + c2) * 64 + l)) * 1024 + s0b + w * 16;
            *(bf16x8*)&tdst[0] = *(const bf16x8*)&tmp[0];
            *(bf16x8*)&tdst[8] = *(const bf16x8*)&tmp[8];
        }
    }
    if (which == 3) {
        __bf16* dst = xg_out + (size_t)(bm * 128) * 512 + (bn & 3) * 128;
#pragma unroll
        for (int p = 0; p < 4; p++) {
            int idx = p * 512 + tid;
            int token = idx >> 4, colv = idx & 15;
            *(bf16x8*)&dst[(size_t)token * 512 + colv * 8] =
                *(const bf16x8*)&sE[token * 136 + colv * 8];
        }
    }
}

// ---------------------------------------------------------------- tail GEMM (64x64, BK=64, depth 3, swizzled)
// MODE 1: proj -> bf16; MODE 2: gate (+xg, sigmoid, mix).
template <int MODE>
__global__ __launch_bounds__(256) void gemm_kernel(
    const __bf16* __restrict__ A, const __bf16* __restrict__ Bw, const float* __restrict__ bias,
    const float* __restrict__ xf, const __bf16* __restrict__ xgb, const __bf16* __restrict__ pvb,
    float* __restrict__ outf, __bf16* __restrict__ outb, int K) {
    __shared__ __bf16 sA[3 * 64 * 64];
    __shared__ __bf16 sB[3 * 64 * 64];
    int bm = blockIdx.x, bn = blockIdx.y;
    int tid = threadIdx.x, w = tid >> 6, l = tid & 63;
    int wr = (w >> 1) * 32, wc = (w & 1) * 32;
    f32x4 acc[2][2] = {};
    const int nt = K / 64;

    auto stage = [&](int t, int buf) {
        int k0 = t * 64;
#pragma unroll
        for (int i = 0; i < 2; i++) {
            int row = i * 32 + w * 8 + (l >> 3);
            int gc = (((l & 7) << 4) ^ ((row & 7) << 4)) >> 1;
            gload16(&A[(size_t)(bm * 64 + row) * K + k0 + gc],
                    &sA[buf * 4096 + i * 2048 + w * 512]);
            gload16(&Bw[(size_t)(bn * 64 + row) * K + k0 + gc],
                    &sB[buf * 4096 + i * 2048 + w * 512]);
        }
    };

    stage(0, 0);
    stage(1, 1);
    for (int t = 0; t < nt; t++) {
        if (t + 1 < nt) asm volatile("s_waitcnt vmcnt(4)" ::: "memory");
        else asm volatile("s_waitcnt vmcnt(0)" ::: "memory");
        asm volatile("s_barrier" ::: "memory");
        if (t + 2 < nt) stage(t + 2, (t + 2) % 3);
        int buf = t % 3;
        bf16x8 af[2][2], bfr[2][2];
#pragma unroll
        for (int kk = 0; kk < 2; kk++) {
            int cb = kk * 64 + ((l >> 4) << 4);
#pragma unroll
            for (int mi = 0; mi < 2; mi++) {
                int rowA = wr + mi * 16 + (l & 15);
                af[kk][mi] = *(const bf16x8*)&sA[buf * 4096 + rowA * 64 +
                                                ((cb ^ ((rowA & 7) << 4)) >> 1)];
            }
#pragma unroll
            for (int ni = 0; ni < 2; ni++) {
                int rowB = wc + ni * 16 + (l & 15);
                bfr[kk][ni] = *(const bf16x8*)&sB[buf * 4096 + rowB * 64 +
                                                 ((cb ^ ((rowB & 7) << 4)) >> 1)];
            }
        }
#pragma unroll
        for (int kk = 0; kk < 2; kk++)
#pragma unroll
            for (int mi = 0; mi < 2; mi++)
#pragma unroll
                for (int ni = 0; ni < 2; ni++)
                    acc[mi][ni] = MFMA16(af[kk][mi], bfr[kk][ni], acc[mi][ni]);
    }

#pragma unroll
    for (int mi = 0; mi < 2; mi++)
#pragma unroll
        for (int ni = 0; ni < 2; ni++)
#pragma unroll
            for (int j = 0; j < 4; j++) {
                int gm = bm * 64 + wr + mi * 16 + ((l >> 4) << 2) + j;
                int gn = bn * 64 + wc + ni * 16 + (l & 15);
                if (MODE == 1) {
                    float v = acc[mi][ni][j] + bias[gn];
                    outb[(size_t)gm * 512 + gn] = (__bf16)v;
                } else {
                    float v = acc[mi][ni][j] + (float)xgb[(size_t)gm * 512 + gn] + bias[gn];
                    float g = 1.f / (1.f + __expf(-v));
                    float xv = xf[(size_t)gm * 512 + gn];
                    float pv = (float)pvb[(size_t)gm * 512 + gn];
                    outf[(size_t)gm * 512 + gn] = xv + g * (pv - xv);
                }
            }
}

// ---------------------------------------------------------------- per-chunk M_c = V^T K + ksum_c (128 blocks)
__global__ __launch_bounds__(256) void mc_kernel(const __bf16* __restrict__ ktb,
                                                 const __bf16* __restrict__ vtb,
                                                 float* __restrict__ Mc, float* __restrict__ ksc) {
    int blk = blockIdx.x;
    int bh = blk >> 3, ch = blk & 7;
    int tid = threadIdx.x, w = tid >> 6, l = tid & 63;
    const __bf16* vb = vtb + (size_t)bh * 65536 + ch * 128;
    const __bf16* kp = ktb + (size_t)bh * 65536 + ch * 128;
    f32x4 macc[4] = {};
#pragma unroll
    for (int ks = 0; ks < 4; ks++) {
        bf16x8 a = *(const bf16x8*)&vb[(size_t)(w * 16 + (l & 15)) * 1024 + ks * 32 + ((l >> 4) << 3)];
#pragma unroll
        for (int ni = 0; ni < 4; ni++) {
            bf16x8 bb = *(const bf16x8*)&kp[(size_t)(ni * 16 + (l & 15)) * 1024 + ks * 32 + ((l >> 4) << 3)];
            macc[ni] = MFMA16(a, bb, macc[ni]);
        }
    }
    float* mout = Mc + (size_t)blk * 4096;
#pragma unroll
    for (int ni = 0; ni < 4; ni++)
#pragma unroll
        for (int j = 0; j < 4; j++)
            mout[(size_t)(w * 16 + ((l >> 4) << 2) + j) * 64 + ni * 16 + (l & 15)] = macc[ni][j];
    if (tid < 64) {
        float s = 0.f;
        const __bf16* kr = ktb + (size_t)(bh * 64 + tid) * 1024 + ch * 128;
#pragma unroll
        for (int t = 0; t < 16; t++) {
            bf16x8 v = *(const bf16x8*)&kr[t * 8];
#pragma unroll
            for (int j = 0; j < 8; j++) s += (float)v[j];
        }
        ksc[blk * 64 + tid] = s;
    }
}

// ---------------------------------------------------------------- attention: 256 blocks (bh, ch, half)
__global__ __launch_bounds__(256) void attn_kernel(
    const __bf16* __restrict__ qb, const __bf16* __restrict__ kb,
    const __bf16* __restrict__ vtb, const float* __restrict__ Mc,
    const float* __restrict__ ksc, __bf16* __restrict__ attn_out) {
    int blk = blockIdx.x;
    int bh = blk >> 4, ch = (blk >> 1) & 7, half = blk & 1;
    int b = bh >> 3, h = bh & 7;
    int tid = threadIdx.x, w = tid >> 6, l = tid & 63;

    __shared__ __bf16 sQ[64 * 72];
    __shared__ __bf16 sP[64 * 136];
    __shared__ __bf16 sM[64 * 72];
    __shared__ float den[64];
    __shared__ float rsum[64];
    __shared__ float ksst[64];

    const __bf16* qsrc = qb + (size_t)(bh * 1024 + ch * 128 + half * 64) * 64;
#pragma unroll
    for (int i = 0; i < 2; i++) {
        int e = i * 2048 + tid * 8;
        *(bf16x8*)&sQ[(e >> 6) * 72 + (e & 63)] = *(const bf16x8*)&qsrc[e];
    }
    {
        int r0 = tid >> 2, c0 = (tid & 3) * 16;
        f32x4 s0 = {}, s1 = {}, s2 = {}, s3 = {};
        const float* mcb = Mc + (size_t)(bh * 8) * 4096 + r0 * 64 + c0;
        for (int c = 0; c < ch; c++) {
            const float* p = mcb + (size_t)c * 4096;
            s0 += *(const f32x4*)&p[0];
            s1 += *(const f32x4*)&p[4];
            s2 += *(const f32x4*)&p[8];
            s3 += *(const f32x4*)&p[12];
        }
        __bf16* d = &sM[r0 * 72 + c0];
#pragma unroll
        for (int j = 0; j < 4; j++) {
            d[j] = (__bf16)s0[j];
            d[4 + j] = (__bf16)s1[j];
            d[8 + j] = (__bf16)s2[j];
            d[12 + j] = (__bf16)s3[j];
        }
    }
    if (tid < 64) {
        float s = 0.f;
        for (int c = 0; c < ch; c++) s += ksc[(bh * 8 + c) * 64 + tid];
        ksst[tid] = s;
    }
    __syncthreads();

    if (tid < 64) {
        float s = 0.f;
#pragma unroll
        for (int d0 = 0; d0 < 64; d0 += 8) {
            bf16x8 qv = *(const bf16x8*)&sQ[tid * 72 + d0];
#pragma unroll
            for (int jj = 0; jj < 8; jj++) s += (float)qv[jj] * ksst[d0 + jj];
        }
        den[tid] = s;
    }

    {
        int wr = w * 16;
        const int CFMAX = half ? (w + 4) : w;
        const int CFLIM = half ? 7 : 3;
        const __bf16* kbase = kb + (size_t)(bh * 1024 + ch * 128) * 64;
        bf16x8 aq[2];
#pragma unroll
        for (int ks = 0; ks < 2; ks++)
            aq[ks] = *(const bf16x8*)&sQ[(wr + (l & 15)) * 72 + ks * 32 + ((l >> 4) << 3)];
        f32x4 acc[8] = {};
#pragma unroll
        for (int cf = 0; cf < 8; cf++) {
            if (cf <= CFMAX && cf <= CFLIM) {
#pragma unroll
                for (int ks = 0; ks < 2; ks++) {
                    bf16x8 bfr = *(const bf16x8*)&kbase[(size_t)(cf * 16 + (l & 15)) * 64 + ks * 32 + ((l >> 4) << 3)];
                    acc[cf] = MFMA16(aq[ks], bfr, acc[cf]);
                }
            }
        }
#pragma unroll
        for (int j = 0; j < 4; j++) {
            int lrow = wr + ((l >> 4) << 2) + j;
            int grow = half * 64 + lrow;
            float rs = 0.f;
#pragma unroll
            for (int cf = 0; cf < 8; cf++) {
                if (cf <= CFMAX && cf <= CFLIM) {
                    int col = cf * 16 + (l & 15);
                    float v = acc[cf][j];
                    v = (col <= grow) ? v : 0.f;
                    rs += v;
                    sP[lrow * 136 + col] = (__bf16)v;
                }
            }
            if (CFMAX + 1 <= CFLIM) sP[lrow * 136 + (CFMAX + 1) * 16 + (l & 15)] = (__bf16)0.f;
#pragma unroll
            for (int off = 1; off < 16; off <<= 1) rs += __shfl_xor(rs, off);
            if ((l & 15) == 0) rsum[lrow] = rs;
        }
    }
    __syncthreads();

    f32x4 o[4] = {};
    {
        int wr = w * 16;
        int ksmax = half ? (2 + (w >> 1)) : (w >> 1);
        const __bf16* vbase = vtb + (size_t)bh * 65536 + ch * 128;
#pragma unroll
        for (int ks = 0; ks < 4; ks++) {
            if (ks <= ksmax) {
                bf16x8 a = *(const bf16x8*)&sP[(wr + (l & 15)) * 136 + ks * 32 + ((l >> 4) << 3)];
#pragma unroll
                for (int ni = 0; ni < 4; ni++) {
                    bf16x8 bfr = *(const bf16x8*)&vbase[(size_t)(ni * 16 + (l & 15)) * 1024 + ks * 32 + ((l >> 4) << 3)];
                    o[ni] = MFMA16(a, bfr, o[ni]);
                }
            }
        }
        if (ch > 0) {
#pragma unroll
            for (int ks = 0; ks < 2; ks++) {
                bf16x8 a = *(const bf16x8*)&sQ[(wr + (l & 15)) * 72 + ks * 32 + ((l >> 4) << 3)];
#pragma unroll
                for (int ni = 0; ni < 4; ni++) {
                    bf16x8 bfr = *(const bf16x8*)&sM[(ni * 16 + (l & 15)) * 72 + ks * 32 + ((l >> 4) << 3)];
                    o[ni] = MFMA16(a, bfr, o[ni]);
                }
            }
        }
    }

    __bf16* obase = attn_out + ((size_t)(b * 1024 + ch * 128 + half * 64)) * 512 + h * 64;
#pragma unroll
    for (int j = 0; j < 4; j++) {
        int lrow = w * 16 + ((l >> 4) << 2) + j;
        float dn = den[lrow] + rsum[lrow] + 1e-6f;
#pragma unroll
        for (int ni = 0; ni < 4; ni++) {
            int col = ni * 16 + (l & 15);
            obase[(size_t)lrow * 512 + col] = (__bf16)(o[ni][j] / dn);
        }
    }
}

// ----------------------------------------------------------------
extern "C" void kernel_launch(void* const* d_in, const int* in_sizes, int n_in,
                              void* d_out, int out_size, void* d_ws, size_t ws_size,
                              hipStream_t stream) {
    const float* x = (const float*)d_in[0];
    const float* Wq = (const float*)d_in[1];
    const float* Wk = (const float*)d_in[2];
    const float* Wv = (const float*)d_in[3];
    const float* Wo = (const float*)d_in[4];
    const float* bo = (const float*)d_in[5];
    const float* Wg = (const float*)d_in[6];
    const float* bg = (const float*)d_in[7];
    float* out = (float*)d_out;

    char* ws = (char*)d_ws;
    size_t off = 0;
    auto alloc = [&](size_t bytes) -> void* {
        void* p = ws + off;
        off += (bytes + 255) & ~(size_t)255;
        return p;
    };
    __bf16* xb    = (__bf16*)alloc((size_t)2048 * 512 * 2);
    __bf16* wqkvT = (__bf16*)alloc((size_t)2048 * 512 * 2);
    __bf16* woT   = (__bf16*)alloc((size_t)512 * 512 * 2);
    __bf16* wg2T  = (__bf16*)alloc((size_t)512 * 512 * 2);
    __bf16* qb    = (__bf16*)alloc((size_t)16 * 1024 * 64 * 2);
    __bf16* kb    = (__bf16*)alloc((size_t)16 * 1024 * 64 * 2);
    __bf16* ktb   = (__bf16*)alloc((size_t)16 * 64 * 1024 * 2);
    __bf16* vtb   = (__bf16*)alloc((size_t)16 * 64 * 1024 * 2);
    float*  Mc    = (float*)alloc((size_t)128 * 4096 * 4);
    float*  ksc   = (float*)alloc((size_t)128 * 64 * 4);
    __bf16* attn  = (__bf16*)alloc((size_t)2048 * 512 * 2);
    __bf16* projb = (__bf16*)alloc((size_t)2048 * 512 * 2);
    __bf16* xgb   = (__bf16*)alloc((size_t)2048 * 512 * 2);

    prep_kernel<<<dim3(16, 32, 6), 256, 0, stream>>>(x, Wq, Wk, Wv, Wo, Wg, xb, wqkvT, woT, wg2T);
    qkv_kernel<<<dim3(16, 16), 512, 0, stream>>>(xb, wqkvT, qb, kb, ktb, vtb, xgb);
    mc_kernel<<<128, 256, 0, stream>>>(ktb, vtb, Mc, ksc);
    attn_kernel<<<256, 256, 0, stream>>>(qb, kb, vtb, Mc, ksc, attn);
    gemm_kernel<1><<<dim3(32, 8), 256, 0, stream>>>(
        attn, woT, bo, nullptr, nullptr, nullptr, nullptr, projb, 512);
    gemm_kernel<2><<<dim3(32, 8), 256, 0, stream>>>(
        projb, wg2T, bg, x, xgb, projb, out, nullptr, 512);
}

// Round 14
// 54.646 us; speedup vs baseline: 2.2153x; 1.0009x over previous
//
#include <hip/hip_runtime.h>
#include <hip/hip_bf16.h>
#include <math.h>

// B=2, S=1024, D=512, H=8, hd=64.  M = B*S = 2048.
// Chunked causal linear attention, chunk C=128, NC=8, BH=16.
// 6 launches: prep(trimmed) -> qkv+xg (128x128, 8-wave) -> mc+transposes(640) -> attn(256) -> proj -> gate.

typedef __bf16 bf16x8 __attribute__((ext_vector_type(8)));
typedef __bf16 bf16x4 __attribute__((ext_vector_type(4)));
typedef float f32x4 __attribute__((ext_vector_type(4)));

#define MFMA16(a, b, c) __builtin_amdgcn_mfma_f32_16x16x32_bf16(a, b, c, 0, 0, 0)

__device__ __forceinline__ float elu1(float v) { return v > 0.f ? v + 1.f : __expf(v); }

__device__ __forceinline__ void gload16(const void* g, void* l) {
    __builtin_amdgcn_global_load_lds((const __attribute__((address_space(1))) void*)g,
                                     (__attribute__((address_space(3))) void*)l, 16, 0, 0);
}

// ---------------------------------------------------------------- prep: x->bf16 + qkv-path transposes only
// z=0..2: {Wq,Wk,Wv} -> wqkvT rows 0..1535; z=3: Wg rows 0..511 -> wqkvT rows 1536..2047; z=4: x conv.
__global__ __launch_bounds__(256) void prep_kernel(
    const float* __restrict__ x, const float* __restrict__ Wq, const float* __restrict__ Wk,
    const float* __restrict__ Wv, const float* __restrict__ Wg,
    __bf16* __restrict__ xb, __bf16* __restrict__ wqkvT) {
    int z = blockIdx.z;
    int tid = threadIdx.x;
    if (z == 4) {
        int bid = blockIdx.y * 16 + blockIdx.x;
        int base = (bid * 256 + tid) * 16;
#pragma unroll
        for (int h = 0; h < 2; h++) {
            bf16x8 o;
#pragma unroll
            for (int j = 0; j < 8; j++) o[j] = (__bf16)x[base + h * 8 + j];
            *(bf16x8*)&xb[base + h * 8] = o;
        }
        return;
    }
    const float* in;
    int noff;
    if (z == 0) { in = Wq; noff = 0; }
    else if (z == 1) { in = Wk; noff = 512; }
    else if (z == 2) { in = Wv; noff = 1024; }
    else { in = Wg; noff = 1536; }
    __shared__ float t[32][33];
    int bx = blockIdx.x, by = blockIdx.y;
    int tx = tid & 31, ty = tid >> 5;
#pragma unroll
    for (int i = 0; i < 32; i += 8)
        t[ty + i][tx] = in[(size_t)(by * 32 + ty + i) * 512 + bx * 32 + tx];
    __syncthreads();
#pragma unroll
    for (int i = 0; i < 32; i += 8) {
        int n = bx * 32 + ty + i;
        int kk = by * 32 + tx;
        wqkvT[(size_t)(noff + n) * 512 + kk] = (__bf16)t[tx][ty + i];
    }
}

// ---------------------------------------------------------------- qkv+xg GEMM: 128x128, 8 waves, BK=64,
// depth-2, 64KB static LDS, T2 swizzle.
__global__ __launch_bounds__(512) void qkv_kernel(
    const __bf16* __restrict__ A, const __bf16* __restrict__ Bw,
    __bf16* __restrict__ q_out, __bf16* __restrict__ k_out,
    __bf16* __restrict__ kt_out, __bf16* __restrict__ vt_out, __bf16* __restrict__ xg_out) {
    __shared__ __bf16 smem[32768];
    __bf16* sA = smem;
    __bf16* sB = smem + 16384;
    int bm = blockIdx.x, bn = blockIdx.y;
    int tid = threadIdx.x, w = tid >> 6, l = tid & 63;
    int wr = (w >> 2) * 64, wc = (w & 3) * 32;
    f32x4 acc[4][2] = {};
    const int nt = 8;

    auto stage = [&](int t, int buf) {
        int k0 = t * 64;
#pragma unroll
        for (int i = 0; i < 2; i++) {
            int row = i * 64 + w * 8 + (l >> 3);
            int gc = (((l & 7) << 4) ^ ((row & 7) << 4)) >> 1;
            gload16(&A[(size_t)(bm * 128 + row) * 512 + k0 + gc],
                    &sA[buf * 8192 + i * 4096 + w * 512]);
            gload16(&Bw[(size_t)(bn * 128 + row) * 512 + k0 + gc],
                    &sB[buf * 8192 + i * 4096 + w * 512]);
        }
    };

    stage(0, 0);
    for (int t = 0; t < nt; t++) {
        asm volatile("s_waitcnt vmcnt(0)" ::: "memory");
        asm volatile("s_barrier" ::: "memory");
        if (t + 1 < nt) stage(t + 1, (t + 1) & 1);
        int buf = t & 1;
#pragma unroll
        for (int kk = 0; kk < 2; kk++) {
            int cb = kk * 64 + ((l >> 4) << 4);
            bf16x8 af[4], bfr[2];
#pragma unroll
            for (int mi = 0; mi < 4; mi++) {
                int rowA = wr + mi * 16 + (l & 15);
                af[mi] = *(const bf16x8*)&sA[buf * 8192 + rowA * 64 +
                                            ((cb ^ ((rowA & 7) << 4)) >> 1)];
            }
#pragma unroll
            for (int ni = 0; ni < 2; ni++) {
                int rowB = wc + ni * 16 + (l & 15);
                bfr[ni] = *(const bf16x8*)&sB[buf * 8192 + rowB * 64 +
                                             ((cb ^ ((rowB & 7) << 4)) >> 1)];
            }
#pragma unroll
            for (int mi = 0; mi < 4; mi++)
#pragma unroll
                for (int ni = 0; ni < 2; ni++)
                    acc[mi][ni] = MFMA16(af[mi], bfr[ni], acc[mi][ni]);
        }
    }

    __bf16* sE = smem;
    __syncthreads();
#pragma unroll
    for (int mi = 0; mi < 4; mi++)
#pragma unroll
        for (int ni = 0; ni < 2; ni++)
#pragma unroll
            for (int j = 0; j < 4; j++) {
                int lr = wr + mi * 16 + ((l >> 4) << 2) + j;
                int lc = wc + ni * 16 + (l & 15);
                float v = acc[mi][ni][j];
                if (bn < 8) v = elu1(v);
                sE[lr * 136 + lc] = (__bf16)v;
            }
    __syncthreads();
    int which = bn >> 2;
    int h0 = (bn & 3) * 2;
    int b = bm >> 3, s0b = (bm & 7) * 128;
    int bh0 = b * 8 + h0;
    if (which == 0 || which == 1) {
        __bf16* qk = (which == 0 ? q_out : k_out);
#pragma unroll
        for (int p = 0; p < 4; p++) {
            int idx = p * 512 + tid;
            int token = idx >> 4, colv = idx & 15;
            int c2 = colv >> 3, d8 = (colv & 7) * 8;
            *(bf16x8*)&qk[((size_t)((bh0 + c2) * 1024 + s0b + token)) * 64 + d8] =
                *(const bf16x8*)&sE[token * 136 + colv * 8];
        }
    }
    if (which == 1 || which == 2) {
        __bf16* tbase = (which == 1 ? kt_out : vt_out);
#pragma unroll
        for (int c2 = 0; c2 < 2; c2++) {
            alignas(16) __bf16 tmp[16];
#pragma unroll
            for (int sj = 0; sj < 16; sj++) tmp[sj] = sE[(w * 16 + sj) * 136 + c2 * 64 + l];
            __bf16* tdst = tbase + ((size_t)((bh0 + c2) * 64 + l)) * 1024 + s0b + w * 16;
            *(bf16x8*)&tdst[0] = *(const bf16x8*)&tmp[0];
            *(bf16x8*)&tdst[8] = *(const bf16x8*)&tmp[8];
        }
    }
    if (which == 3) {
        __bf16* dst = xg_out + (size_t)(bm * 128) * 512 + (bn & 3) * 128;
#pragma unroll
        for (int p = 0; p < 4; p++) {
            int idx = p * 512 + tid;
            int token = idx >> 4, colv = idx & 15;
            *(bf16x8*)&dst[(size_t)token * 512 + colv * 8] =
                *(const bf16x8*)&sE[token * 136 + colv * 8];
        }
    }
}

// ---------------------------------------------------------------- mc (blocks 0..127) + tail-weight
// transposes (blocks 128..639: 256 Wo tiles, 256 Wg2 tiles) in one launch.
__global__ __launch_bounds__(256) void mc_kernel(
    const __bf16* __restrict__ ktb, const __bf16* __restrict__ vtb,
    float* __restrict__ Mc, float* __restrict__ ksc,
    const float* __restrict__ Wo, const float* __restrict__ Wg,
    __bf16* __restrict__ woT, __bf16* __restrict__ wg2T) {
    int blk = blockIdx.x;
    int tid = threadIdx.x, w = tid >> 6, l = tid & 63;
    if (blk >= 128) {
        // transpose tile: Wo (t6<256) or Wg rows 512..1023 -> wg2T
        int t6 = blk - 128;
        const float* in;
        __bf16* out;
        int local;
        if (t6 < 256) { in = Wo; out = woT; local = t6; }
        else { in = Wg + (size_t)512 * 512; out = wg2T; local = t6 - 256; }
        int by = local >> 4, bx = local & 15;
        __shared__ float t[32][33];
        int tx = tid & 31, ty = tid >> 5;
#pragma unroll
        for (int i = 0; i < 32; i += 8)
            t[ty + i][tx] = in[(size_t)(by * 32 + ty + i) * 512 + bx * 32 + tx];
        __syncthreads();
#pragma unroll
        for (int i = 0; i < 32; i += 8)
            out[(size_t)(bx * 32 + ty + i) * 512 + by * 32 + tx] = (__bf16)t[tx][ty + i];
        return;
    }
    int bh = blk >> 3, ch = blk & 7;
    const __bf16* vb = vtb + (size_t)bh * 65536 + ch * 128;
    const __bf16* kp = ktb + (size_t)bh * 65536 + ch * 128;
    f32x4 macc[4] = {};
#pragma unroll
    for (int ks = 0; ks < 4; ks++) {
        bf16x8 a = *(const bf16x8*)&vb[(size_t)(w * 16 + (l & 15)) * 1024 + ks * 32 + ((l >> 4) << 3)];
#pragma unroll
        for (int ni = 0; ni < 4; ni++) {
            bf16x8 bb = *(const bf16x8*)&kp[(size_t)(ni * 16 + (l & 15)) * 1024 + ks * 32 + ((l >> 4) << 3)];
            macc[ni] = MFMA16(a, bb, macc[ni]);
        }
    }
    float* mout = Mc + (size_t)blk * 4096;
#pragma unroll
    for (int ni = 0; ni < 4; ni++)
#pragma unroll
        for (int j = 0; j < 4; j++)
            mout[(size_t)(w * 16 + ((l >> 4) << 2) + j) * 64 + ni * 16 + (l & 15)] = macc[ni][j];
    if (tid < 64) {
        float s = 0.f;
        const __bf16* kr = ktb + (size_t)(bh * 64 + tid) * 1024 + ch * 128;
#pragma unroll
        for (int t = 0; t < 16; t++) {
            bf16x8 v = *(const bf16x8*)&kr[t * 8];
#pragma unroll
            for (int j = 0; j < 8; j++) s += (float)v[j];
        }
        ksc[blk * 64 + tid] = s;
    }
}

// ---------------------------------------------------------------- attention: 256 blocks (bh, ch, half)
__global__ __launch_bounds__(256) void attn_kernel(
    const __bf16* __restrict__ qb, const __bf16* __restrict__ kb,
    const __bf16* __restrict__ vtb, const float* __restrict__ Mc,
    const float* __restrict__ ksc, __bf16* __restrict__ attn_out) {
    int blk = blockIdx.x;
    int bh = blk >> 4, ch = (blk >> 1) & 7, half = blk & 1;
    int b = bh >> 3, h = bh & 7;
    int tid = threadIdx.x, w = tid >> 6, l = tid & 63;

    __shared__ __bf16 sQ[64 * 72];
    __shared__ __bf16 sP[64 * 136];
    __shared__ __bf16 sM[64 * 72];
    __shared__ float den[64];
    __shared__ float rsum[64];
    __shared__ float ksst[64];

    const __bf16* qsrc = qb + (size_t)(bh * 1024 + ch * 128 + half * 64) * 64;
#pragma unroll
    for (int i = 0; i < 2; i++) {
        int e = i * 2048 + tid * 8;
        *(bf16x8*)&sQ[(e >> 6) * 72 + (e & 63)] = *(const bf16x8*)&qsrc[e];
    }
    {
        int r0 = tid >> 2, c0 = (tid & 3) * 16;
        f32x4 s0 = {}, s1 = {}, s2 = {}, s3 = {};
        const float* mcb = Mc + (size_t)(bh * 8) * 4096 + r0 * 64 + c0;
        for (int c = 0; c < ch; c++) {
            const float* p = mcb + (size_t)c * 4096;
            s0 += *(const f32x4*)&p[0];
            s1 += *(const f32x4*)&p[4];
            s2 += *(const f32x4*)&p[8];
            s3 += *(const f32x4*)&p[12];
        }
        __bf16* d = &sM[r0 * 72 + c0];
#pragma unroll
        for (int j = 0; j < 4; j++) {
            d[j] = (__bf16)s0[j];
            d[4 + j] = (__bf16)s1[j];
            d[8 + j] = (__bf16)s2[j];
            d[12 + j] = (__bf16)s3[j];
        }
    }
    if (tid < 64) {
        float s = 0.f;
        for (int c = 0; c < ch; c++) s += ksc[(bh * 8 + c) * 64 + tid];
        ksst[tid] = s;
    }
    __syncthreads();

    if (tid < 64) {
        float s = 0.f;
#pragma unroll
        for (int d0 = 0; d0 < 64; d0 += 8) {
            bf16x8 qv = *(const bf16x8*)&sQ[tid * 72 + d0];
#pragma unroll
            for (int jj = 0; jj < 8; jj++) s += (float)qv[jj] * ksst[d0 + jj];
        }
        den[tid] = s;
    }

    {
        int wr = w * 16;
        const int CFMAX = half ? (w + 4) : w;
        const int CFLIM = half ? 7 : 3;
        const __bf16* kbase = kb + (size_t)(bh * 1024 + ch * 128) * 64;
        bf16x8 aq[2];
#pragma unroll
        for (int ks = 0; ks < 2; ks++)
            aq[ks] = *(const bf16x8*)&sQ[(wr + (l & 15)) * 72 + ks * 32 + ((l >> 4) << 3)];
        f32x4 acc[8] = {};
#pragma unroll
        for (int cf = 0; cf < 8; cf++) {
            if (cf <= CFMAX && cf <= CFLIM) {
#pragma unroll
                for (int ks = 0; ks < 2; ks++) {
                    bf16x8 bfr = *(const bf16x8*)&kbase[(size_t)(cf * 16 + (l & 15)) * 64 + ks * 32 + ((l >> 4) << 3)];
                    acc[cf] = MFMA16(aq[ks], bfr, acc[cf]);
                }
            }
        }
#pragma unroll
        for (int j = 0; j < 4; j++) {
            int lrow = wr + ((l >> 4) << 2) + j;
            int grow = half * 64 + lrow;
            float rs = 0.f;
#pragma unroll
            for (int cf = 0; cf < 8; cf++) {
                if (cf <= CFMAX && cf <= CFLIM) {
                    int col = cf * 16 + (l & 15);
                    float v = acc[cf][j];
                    v = (col <= grow) ? v : 0.f;
                    rs += v;
                    sP[lrow * 136 + col] = (__bf16)v;
                }
            }
            if (CFMAX + 1 <= CFLIM) sP[lrow * 136 + (CFMAX + 1) * 16 + (l & 15)] = (__bf16)0.f;
#pragma unroll
            for (int off = 1; off < 16; off <<= 1) rs += __shfl_xor(rs, off);
            if ((l & 15) == 0) rsum[lrow] = rs;
        }
    }
    __syncthreads();

    f32x4 o[4] = {};
    {
        int wr = w * 16;
        int ksmax = half ? (2 + (w >> 1)) : (w >> 1);
        const __bf16* vbase = vtb + (size_t)bh * 65536 + ch * 128;
#pragma unroll
        for (int ks = 0; ks < 4; ks++) {
            if (ks <= ksmax) {
                bf16x8 a = *(const bf16x8*)&sP[(wr + (l & 15)) * 136 + ks * 32 + ((l >> 4) << 3)];
#pragma unroll
                for (int ni = 0; ni < 4; ni++) {
                    bf16x8 bfr = *(const bf16x8*)&vbase[(size_t)(ni * 16 + (l & 15)) * 1024 + ks * 32 + ((l >> 4) << 3)];
                    o[ni] = MFMA16(a, bfr, o[ni]);
                }
            }
        }
        if (ch > 0) {
#pragma unroll
            for (int ks = 0; ks < 2; ks++) {
                bf16x8 a = *(const bf16x8*)&sQ[(wr + (l & 15)) * 72 + ks * 32 + ((l >> 4) << 3)];
#pragma unroll
                for (int ni = 0; ni < 4; ni++) {
                    bf16x8 bfr = *(const bf16x8*)&sM[(ni * 16 + (l & 15)) * 72 + ks * 32 + ((l >> 4) << 3)];
                    o[ni] = MFMA16(a, bfr, o[ni]);
                }
            }
        }
    }

    __bf16* obase = attn_out + ((size_t)(b * 1024 + ch * 128 + half * 64)) * 512 + h * 64;
#pragma unroll
    for (int j = 0; j < 4; j++) {
        int lrow = w * 16 + ((l >> 4) << 2) + j;
        float dn = den[lrow] + rsum[lrow] + 1e-6f;
#pragma unroll
        for (int ni = 0; ni < 4; ni++) {
            int col = ni * 16 + (l & 15);
            obase[(size_t)lrow * 512 + col] = (__bf16)(o[ni][j] / dn);
        }
    }
}

// ---------------------------------------------------------------- tail GEMM (64x64, BK=64, depth 3, swizzled)
template <int MODE>
__global__ __launch_bounds__(256) void gemm_kernel(
    const __bf16* __restrict__ A, const __bf16* __restrict__ Bw, const float* __restrict__ bias,
    const float* __restrict__ xf, const __bf16* __restrict__ xgb, const __bf16* __restrict__ pvb,
    float* __restrict__ outf, __bf16* __restrict__ outb, int K) {
    __shared__ __bf16 sA[3 * 64 * 64];
    __shared__ __bf16 sB[3 * 64 * 64];
    int bm = blockIdx.x, bn = blockIdx.y;
    int tid = threadIdx.x, w = tid >> 6, l = tid & 63;
    int wr = (w >> 1) * 32, wc = (w & 1) * 32;
    f32x4 acc[2][2] = {};
    const int nt = K / 64;

    auto stage = [&](int t, int buf) {
        int k0 = t * 64;
#pragma unroll
        for (int i = 0; i < 2; i++) {
            int row = i * 32 + w * 8 + (l >> 3);
            int gc = (((l & 7) << 4) ^ ((row & 7) << 4)) >> 1;
            gload16(&A[(size_t)(bm * 64 + row) * K + k0 + gc],
                    &sA[buf * 4096 + i * 2048 + w * 512]);
            gload16(&Bw[(size_t)(bn * 64 + row) * K + k0 + gc],
                    &sB[buf * 4096 + i * 2048 + w * 512]);
        }
    };

    stage(0, 0);
    stage(1, 1);
    for (int t = 0; t < nt; t++) {
        if (t + 1 < nt) asm volatile("s_waitcnt vmcnt(4)" ::: "memory");
        else asm volatile("s_waitcnt vmcnt(0)" ::: "memory");
        asm volatile("s_barrier" ::: "memory");
        if (t + 2 < nt) stage(t + 2, (t + 2) % 3);
        int buf = t % 3;
        bf16x8 af[2][2], bfr[2][2];
#pragma unroll
        for (int kk = 0; kk < 2; kk++) {
            int cb = kk * 64 + ((l >> 4) << 4);
#pragma unroll
            for (int mi = 0; mi < 2; mi++) {
                int rowA = wr + mi * 16 + (l & 15);
                af[kk][mi] = *(const bf16x8*)&sA[buf * 4096 + rowA * 64 +
                                                ((cb ^ ((rowA & 7) << 4)) >> 1)];
            }
#pragma unroll
            for (int ni = 0; ni < 2; ni++) {
                int rowB = wc + ni * 16 + (l & 15);
                bfr[kk][ni] = *(const bf16x8*)&sB[buf * 4096 + rowB * 64 +
                                                 ((cb ^ ((rowB & 7) << 4)) >> 1)];
            }
        }
#pragma unroll
        for (int kk = 0; kk < 2; kk++)
#pragma unroll
            for (int mi = 0; mi < 2; mi++)
#pragma unroll
                for (int ni = 0; ni < 2; ni++)
                    acc[mi][ni] = MFMA16(af[kk][mi], bfr[kk][ni], acc[mi][ni]);
    }

#pragma unroll
    for (int mi = 0; mi < 2; mi++)
#pragma unroll
        for (int ni = 0; ni < 2; ni++)
#pragma unroll
            for (int j = 0; j < 4; j++) {
                int gm = bm * 64 + wr + mi * 16 + ((l >> 4) << 2) + j;
                int gn = bn * 64 + wc + ni * 16 + (l & 15);
                if (MODE == 1) {
                    float v = acc[mi][ni][j] + bias[gn];
                    outb[(size_t)gm * 512 + gn] = (__bf16)v;
                } else {
                    float v = acc[mi][ni][j] + (float)xgb[(size_t)gm * 512 + gn] + bias[gn];
                    float g = 1.f / (1.f + __expf(-v));
                    float xv = xf[(size_t)gm * 512 + gn];
                    float pv = (float)pvb[(size_t)gm * 512 + gn];
                    outf[(size_t)gm * 512 + gn] = xv + g * (pv - xv);
                }
            }
}

// ----------------------------------------------------------------
extern "C" void kernel_launch(void* const* d_in, const int* in_sizes, int n_in,
                              void* d_out, int out_size, void* d_ws, size_t ws_size,
                              hipStream_t stream) {
    const float* x = (const float*)d_in[0];
    const float* Wq = (const float*)d_in[1];
    const float* Wk = (const float*)d_in[2];
    const float* Wv = (const float*)d_in[3];
    const float* Wo = (const float*)d_in[4];
    const float* bo = (const float*)d_in[5];
    const float* Wg = (const float*)d_in[6];
    const float* bg = (const float*)d_in[7];
    float* out = (float*)d_out;

    char* ws = (char*)d_ws;
    size_t off = 0;
    auto alloc = [&](size_t bytes) -> void* {
        void* p = ws + off;
        off += (bytes + 255) & ~(size_t)255;
        return p;
    };
    __bf16* xb    = (__bf16*)alloc((size_t)2048 * 512 * 2);
    __bf16* wqkvT = (__bf16*)alloc((size_t)2048 * 512 * 2);
    __bf16* woT   = (__bf16*)alloc((size_t)512 * 512 * 2);
    __bf16* wg2T  = (__bf16*)alloc((size_t)512 * 512 * 2);
    __bf16* qb    = (__bf16*)alloc((size_t)16 * 1024 * 64 * 2);
    __bf16* kb    = (__bf16*)alloc((size_t)16 * 1024 * 64 * 2);
    __bf16* ktb   = (__bf16*)alloc((size_t)16 * 64 * 1024 * 2);
    __bf16* vtb   = (__bf16*)alloc((size_t)16 * 64 * 1024 * 2);
    float*  Mc    = (float*)alloc((size_t)128 * 4096 * 4);
    float*  ksc   = (float*)alloc((size_t)128 * 64 * 4);
    __bf16* attn  = (__bf16*)alloc((size_t)2048 * 512 * 2);
    __bf16* projb = (__bf16*)alloc((size_t)2048 * 512 * 2);
    __bf16* xgb   = (__bf16*)alloc((size_t)2048 * 512 * 2);

    prep_kernel<<<dim3(16, 16, 5), 256, 0, stream>>>(x, Wq, Wk, Wv, Wg, xb, wqkvT);
    qkv_kernel<<<dim3(16, 16), 512, 0, stream>>>(xb, wqkvT, qb, kb, ktb, vtb, xgb);
    mc_kernel<<<640, 256, 0, stream>>>(ktb, vtb, Mc, ksc, Wo, Wg, woT, wg2T);
    attn_kernel<<<256, 256, 0, stream>>>(qb, kb, vtb, Mc, ksc, attn);
    gemm_kernel<1><<<dim3(32, 8), 256, 0, stream>>>(
        attn, woT, bo, nullptr, nullptr, nullptr, nullptr, projb, 512);
    gemm_kernel<2><<<dim3(32, 8), 256, 0, stream>>>(
        projb, wg2T, bg, x, xgb, projb, out, nullptr, 512);
}